// Round 2
// baseline (1878.466 us; speedup 1.0000x reference)
//
#include <hip/hip_runtime.h>
#include <math.h>

// DHVT block, fp32 baseline. B=128 N=197 C=384 H=6 HD=64 HID=1536 S=14 M=203.
// Round 1: resubmission of round-0 kernel (both prior benches died in
// GPU acquisition; no evidence to act on yet).
#define B_   128
#define N_   197
#define C_   384
#define H_   6
#define HD_  64
#define HID_ 1536
#define S_   14
#define M_   203
#define P_   196
#define TC_  1152  // 3*C

// ---- workspace layout (floats). Region A reused: xa -> proj -> xn2 -> y.
// Region B reused: qkv+aout -> h. Total 239.1 MB.
static constexpr size_t A_OFF    = 0;          // 9,977,856 floats (B*M*C)
static constexpr size_t B_OFF    = 9977856;    // qkv: B*M*3C = 29,933,568 ; later h: B*196*HID
static constexpr size_t AOUT_OFF = 39911424;   // B*M*C
static constexpr size_t X1_OFF   = 49889280;   // B*N*C = 9,682,944
static constexpr size_t CLS2_OFF = 59572224;   // B*C
static constexpr size_t HM_OFF   = 59621376;   // B*C
static constexpr size_t YM_OFF   = 59670528;   // B*C
static constexpr size_t WSE_OFF  = 59719680;   // B*C
static constexpr size_t WS_FLOATS= 59768832;

__device__ __forceinline__ float gelu_f(float x) {
    return 0.5f * x * (1.0f + erff(x * 0.70710678118654752440f));
}
__device__ __forceinline__ float wave_sum(float v) {
    #pragma unroll
    for (int o = 32; o > 0; o >>= 1) v += __shfl_xor(v, o);
    return v;
}
__device__ __forceinline__ float wave_max(float v) {
    #pragma unroll
    for (int o = 32; o > 0; o >>= 1) v = fmaxf(v, __shfl_xor(v, o));
    return v;
}

// ---- LN over C=384, one wave per row. Writes xa rows [0,197) of each image.
__global__ __launch_bounds__(256) void k_ln1(const float* __restrict__ x,
        const float* __restrict__ g, const float* __restrict__ bt, float* __restrict__ xa)
{
    int row = blockIdx.x * 4 + (threadIdx.x >> 6);
    if (row >= B_ * N_) return;
    int lane = threadIdx.x & 63;
    int b = row / N_, n = row % N_;
    const float* xr = x + (size_t)row * C_;
    float v[6], s = 0.f, sq = 0.f;
    #pragma unroll
    for (int i = 0; i < 6; ++i) { v[i] = xr[lane + 64*i]; s += v[i]; sq += v[i]*v[i]; }
    s = wave_sum(s); sq = wave_sum(sq);
    float mean = s * (1.0f / C_);
    float var  = sq * (1.0f / C_) - mean * mean;
    float rstd = rsqrtf(var + 1e-5f);
    float* orow = xa + ((size_t)b * M_ + n) * C_;
    #pragma unroll
    for (int i = 0; i < 6; ++i) {
        int c = lane + 64*i;
        orow[c] = (v[i] - mean) * rstd * g[c] + bt[c];
    }
}

// ---- mean over the N=197 normalized tokens -> hm (B,C)
__global__ void k_head_mean(const float* __restrict__ xa, float* __restrict__ hm)
{
    int b = blockIdx.x, c = threadIdx.x;  // 384 threads
    float s = 0.f;
    for (int n = 0; n < N_; ++n) s += xa[((size_t)b * M_ + n) * C_ + c];
    hm[b * C_ + c] = s * (1.0f / N_);
}

// ---- head tokens: hm.reshape(H,HD) @ ht_w + ht_b -> LN64 -> gelu -> +pos; xa rows [197,203)
__global__ __launch_bounds__(384) void k_head_tokens(const float* __restrict__ hm,
    const float* __restrict__ ht_w, const float* __restrict__ ht_b,
    const float* __restrict__ htn_g, const float* __restrict__ htn_b,
    const float* __restrict__ pos, float* __restrict__ xa)
{
    __shared__ float hs[C_];
    int b = blockIdx.x, c = threadIdx.x, lane = c & 63;
    hs[c] = hm[b * C_ + c];
    __syncthreads();
    for (int h1 = 0; h1 < H_; ++h1) {
        float acc = ht_b[c];
        #pragma unroll 8
        for (int d = 0; d < HD_; ++d) acc += hs[h1*HD_ + d] * ht_w[d*C_ + c];
        // LN over each 64-group: wave == group (c = h2*64 + lane)
        float mean = wave_sum(acc) * (1.0f / HD_);
        float sq   = wave_sum(acc*acc) * (1.0f / HD_);
        float var  = sq - mean*mean;
        float nv = (acc - mean) * rsqrtf(var + 1e-5f) * htn_g[lane] + htn_b[lane];
        xa[((size_t)b*M_ + N_ + h1)*C_ + c] = gelu_f(nv) + pos[h1*C_ + c];
    }
}

// ---- fp32 tiled GEMM, 64x64 tile, BK=32, 256 threads, 4x4 per thread.
// EPI 0: out = acc+bias ; 1: gelu((acc+bias)*g*R + b) ; 2: (acc+bias)*g*R + b
template<int EPI>
__global__ __launch_bounds__(256) void k_gemm(const float* __restrict__ A,
    const float* __restrict__ Bm, float* __restrict__ Cm,
    const float* __restrict__ bias, const float* __restrict__ bng,
    const float* __restrict__ bnb, int K, int Nc)
{
    __shared__ float As[32][68];  // k-major, pad 68 keeps rows 16B-aligned
    __shared__ float Bs[32][64];
    int tid = threadIdx.x;
    int tx = tid & 15, ty = tid >> 4;
    int m_base = blockIdx.y * 64, n_base = blockIdx.x * 64;
    float acc[4][4] = {};
    for (int k0 = 0; k0 < K; k0 += 32) {
        #pragma unroll
        for (int l = 0; l < 2; ++l) {
            int cidx = tid + l * 256;
            int r = cidx >> 3, kc = (cidx & 7) << 2;
            float4 va = *(const float4*)(A + (size_t)(m_base + r) * K + k0 + kc);
            As[kc+0][r] = va.x; As[kc+1][r] = va.y; As[kc+2][r] = va.z; As[kc+3][r] = va.w;
            int kb = cidx >> 4, nc2 = (cidx & 15) << 2;
            *(float4*)&Bs[kb][nc2] = *(const float4*)(Bm + (size_t)(k0 + kb) * Nc + n_base + nc2);
        }
        __syncthreads();
        #pragma unroll
        for (int kk = 0; kk < 32; ++kk) {
            float4 a4 = *(const float4*)&As[kk][ty*4];
            float4 b4 = *(const float4*)&Bs[kk][tx*4];
            float av[4] = {a4.x, a4.y, a4.z, a4.w};
            float bv[4] = {b4.x, b4.y, b4.z, b4.w};
            #pragma unroll
            for (int i = 0; i < 4; ++i)
                #pragma unroll
                for (int j = 0; j < 4; ++j)
                    acc[i][j] = fmaf(av[i], bv[j], acc[i][j]);
        }
        __syncthreads();
    }
    int n0 = n_base + tx*4;
    const float R_ = 0.99999500003749969f;  // rsqrt(1+1e-5)
    float bia[4], sc_[4] = {1.f,1.f,1.f,1.f}, sh_[4] = {0.f,0.f,0.f,0.f};
    #pragma unroll
    for (int j = 0; j < 4; ++j) bia[j] = bias[n0+j];
    if (EPI >= 1) {
        #pragma unroll
        for (int j = 0; j < 4; ++j) { sc_[j] = bng[n0+j] * R_; sh_[j] = bnb[n0+j]; }
    }
    #pragma unroll
    for (int i = 0; i < 4; ++i) {
        float tmp[4];
        #pragma unroll
        for (int j = 0; j < 4; ++j) {
            float v = acc[i][j] + bia[j];
            if (EPI >= 1) v = v * sc_[j] + sh_[j];
            if (EPI == 1) v = gelu_f(v);
            tmp[j] = v;
        }
        float4 o; o.x = tmp[0]; o.y = tmp[1]; o.z = tmp[2]; o.w = tmp[3];
        *(float4*)(Cm + (size_t)(m_base + ty*4 + i) * Nc + n0) = o;
    }
}

// ---- attention: one block per (b,h), 512 threads (8 waves). K transposed + V staged in LDS.
__global__ __launch_bounds__(512) void k_attn(const float* __restrict__ qkv, float* __restrict__ aout)
{
    __shared__ float Kt[64][204];    // [d][j], rows 16B-aligned
    __shared__ float Vs[203][64];    // [j][d], 2-way (free) on lane=d reads
    __shared__ float Pw[8][4][204];  // per-wave per-query probabilities
    int b = blockIdx.x / H_, h = blockIdx.x % H_;
    const float* qbase = qkv + (size_t)b * M_ * TC_ + h * HD_;
    for (int idx = threadIdx.x; idx < M_ * 64; idx += 512) {
        int j = idx >> 6, d = idx & 63;
        Kt[d][j] = qbase[(size_t)j * TC_ + 384 + d];
        Vs[j][d] = qbase[(size_t)j * TC_ + 768 + d];
    }
    __syncthreads();
    int wave = threadIdx.x >> 6, lane = threadIdx.x & 63;
    bool lact = (lane < 51);  // 51 lanes * 4 keys >= 203
    for (int mq = wave; mq < 51; mq += 8) {
        int q0 = mq * 4;
        int qidx[4];
        float sc[4][4];
        #pragma unroll
        for (int a = 0; a < 4; ++a) {
            qidx[a] = (q0 + a < M_) ? (q0 + a) : (M_ - 1);
            #pragma unroll
            for (int i = 0; i < 4; ++i) sc[a][i] = 0.f;
        }
        if (lact) {
            #pragma unroll 4
            for (int d = 0; d < 64; d += 4) {
                float4 k0 = *(const float4*)&Kt[d+0][lane*4];
                float4 k1 = *(const float4*)&Kt[d+1][lane*4];
                float4 k2 = *(const float4*)&Kt[d+2][lane*4];
                float4 k3 = *(const float4*)&Kt[d+3][lane*4];
                #pragma unroll
                for (int a = 0; a < 4; ++a) {
                    float4 qv = *(const float4*)(qbase + (size_t)qidx[a] * TC_ + d);
                    sc[a][0] += qv.x*k0.x + qv.y*k1.x + qv.z*k2.x + qv.w*k3.x;
                    sc[a][1] += qv.x*k0.y + qv.y*k1.y + qv.z*k2.y + qv.w*k3.y;
                    sc[a][2] += qv.x*k0.z + qv.y*k1.z + qv.z*k2.z + qv.w*k3.z;
                    sc[a][3] += qv.x*k0.w + qv.y*k1.w + qv.z*k2.w + qv.w*k3.w;
                }
            }
        }
        #pragma unroll
        for (int a = 0; a < 4; ++a) {
            float mx = -1e30f;
            #pragma unroll
            for (int i = 0; i < 4; ++i) {
                int key = lane*4 + i;
                float sv = (lact && key < M_) ? sc[a][i] * 0.125f : -1e30f;
                sc[a][i] = sv;
                mx = fmaxf(mx, sv);
            }
            mx = wave_max(mx);
            float sm = 0.f;
            #pragma unroll
            for (int i = 0; i < 4; ++i) {
                float e = (sc[a][i] > -1e29f) ? __expf(sc[a][i] - mx) : 0.f;
                sc[a][i] = e;
                sm += e;
            }
            sm = wave_sum(sm);
            float inv = 1.0f / sm;
            if (lact) {
                #pragma unroll
                for (int i = 0; i < 4; ++i) Pw[wave][a][lane*4+i] = sc[a][i] * inv;
            }
        }
        // wave-local LDS producer->consumer: force the P writes to land
        asm volatile("s_waitcnt lgkmcnt(0)" ::: "memory");
        float oacc[4] = {0.f, 0.f, 0.f, 0.f};
        for (int j = 0; j < 200; j += 4) {
            float4 p0 = *(const float4*)&Pw[wave][0][j];
            float4 p1 = *(const float4*)&Pw[wave][1][j];
            float4 p2 = *(const float4*)&Pw[wave][2][j];
            float4 p3 = *(const float4*)&Pw[wave][3][j];
            float v0 = Vs[j+0][lane], v1 = Vs[j+1][lane], v2 = Vs[j+2][lane], v3 = Vs[j+3][lane];
            oacc[0] += p0.x*v0 + p0.y*v1 + p0.z*v2 + p0.w*v3;
            oacc[1] += p1.x*v0 + p1.y*v1 + p1.z*v2 + p1.w*v3;
            oacc[2] += p2.x*v0 + p2.y*v1 + p2.z*v2 + p2.w*v3;
            oacc[3] += p3.x*v0 + p3.y*v1 + p3.z*v2 + p3.w*v3;
        }
        #pragma unroll
        for (int j = 200; j < 203; ++j) {
            float v = Vs[j][lane];
            oacc[0] += Pw[wave][0][j] * v;
            oacc[1] += Pw[wave][1][j] * v;
            oacc[2] += Pw[wave][2][j] * v;
            oacc[3] += Pw[wave][3][j] * v;
        }
        #pragma unroll
        for (int a = 0; a < 4; ++a)
            if (q0 + a < M_)
                aout[((size_t)b*M_ + q0 + a)*C_ + h*HD_ + lane] = oacc[a];
    }
}

// ---- x1 = x + [cls, proj rows 1..196] ; cls = proj[0] + mean(proj rows 197..202)
__global__ void k_build_x1(const float* __restrict__ x, const float* __restrict__ proj,
                           float* __restrict__ x1)
{
    size_t idx = (size_t)blockIdx.x * 256 + threadIdx.x;
    if (idx >= (size_t)B_*N_*C_) return;
    int c = (int)(idx % C_);
    size_t t = idx / C_;
    int n = (int)(t % N_); int b = (int)(t / N_);
    const float* pr = proj + (size_t)b * M_ * C_;
    float v = x[idx];
    if (n == 0) {
        float s = 0.f;
        #pragma unroll
        for (int m = 0; m < H_; ++m) s += pr[(size_t)(N_ + m) * C_ + c];
        v += pr[c] + s * (1.0f / H_);
    } else {
        v += pr[(size_t)n * C_ + c];
    }
    x1[idx] = v;
}

// ---- LN2: row 0 -> cls2 (B,C); rows 1..196 -> xn2 tokens (B,196,C)
__global__ __launch_bounds__(256) void k_ln2(const float* __restrict__ x1,
    const float* __restrict__ g, const float* __restrict__ bt,
    float* __restrict__ xn2, float* __restrict__ cls2)
{
    int row = blockIdx.x * 4 + (threadIdx.x >> 6);
    if (row >= B_ * N_) return;
    int lane = threadIdx.x & 63;
    int b = row / N_, n = row % N_;
    const float* xr = x1 + (size_t)row * C_;
    float v[6], s = 0.f, sq = 0.f;
    #pragma unroll
    for (int i = 0; i < 6; ++i) { v[i] = xr[lane + 64*i]; s += v[i]; sq += v[i]*v[i]; }
    s = wave_sum(s); sq = wave_sum(sq);
    float mean = s * (1.0f / C_);
    float var  = sq * (1.0f / C_) - mean * mean;
    float rstd = rsqrtf(var + 1e-5f);
    float* orow = (n == 0) ? (cls2 + (size_t)b * C_)
                           : (xn2 + ((size_t)b * P_ + (n - 1)) * C_);
    #pragma unroll
    for (int i = 0; i < 6; ++i) {
        int c = lane + 64*i;
        orow[c] = (v[i] - mean) * rstd * g[c] + bt[c];
    }
}

// ---- depthwise 3x3 SAME + BN + gelu + residual, in place on h (B,196,HID).
__global__ __launch_bounds__(256) void k_dwconv(float* __restrict__ h,
    const float* __restrict__ w, const float* __restrict__ c2b,
    const float* __restrict__ g2, const float* __restrict__ b2)
{
    __shared__ float tile[P_][64];
    __shared__ float wl[64][9];
    int b = blockIdx.x, ch0 = blockIdx.y * 64;
    for (int idx = threadIdx.x; idx < P_ * 64; idx += 256) {
        int p = idx >> 6, c = idx & 63;
        tile[p][c] = h[((size_t)b * P_ + p) * HID_ + ch0 + c];
    }
    if (threadIdx.x < 64) {
        int c = threadIdx.x;
        #pragma unroll
        for (int k = 0; k < 9; ++k) wl[c][k] = w[(ch0 + c) * 9 + k];
    }
    __syncthreads();
    const float R_ = 0.99999500003749969f;
    for (int idx = threadIdx.x; idx < P_ * 64; idx += 256) {
        int p = idx >> 6, c = idx & 63;
        int y = p / S_, xq = p % S_;
        float a = 0.f;
        #pragma unroll
        for (int dy = 0; dy < 3; ++dy) {
            int yy = y + dy - 1;
            if (yy < 0 || yy >= S_) continue;
            #pragma unroll
            for (int dx = 0; dx < 3; ++dx) {
                int xx = xq + dx - 1;
                if (xx < 0 || xx >= S_) continue;
                a += wl[c][dy*3+dx] * tile[yy*S_ + xx][c];
            }
        }
        int ch = ch0 + c;
        float val = (a + c2b[ch]) * (g2[ch] * R_) + b2[ch];
        h[((size_t)b * P_ + p) * HID_ + ch] = tile[p][c] + gelu_f(val);
    }
}

// ---- spatial mean of y -> ym (B,C)
__global__ void k_ymean(const float* __restrict__ y, float* __restrict__ ym)
{
    int b = blockIdx.x, c = threadIdx.x;  // 384
    float s = 0.f;
    for (int p = 0; p < P_; ++p) s += y[((size_t)b * P_ + p) * C_ + c];
    ym[b * C_ + c] = s * (1.0f / P_);
}

// ---- SE: w = gelu(ym @ cmp_w + cmp_b) @ exc_w + exc_b
__global__ __launch_bounds__(384) void k_se(const float* __restrict__ ym,
    const float* __restrict__ cw, const float* __restrict__ cb,
    const float* __restrict__ ew, const float* __restrict__ eb, float* __restrict__ wse)
{
    __shared__ float ys[C_];
    __shared__ float hid[96];
    int b = blockIdx.x, t = threadIdx.x;
    ys[t] = ym[b * C_ + t];
    __syncthreads();
    if (t < 96) {
        float a = cb[t];
        for (int c = 0; c < C_; ++c) a += ys[c] * cw[c * 96 + t];
        hid[t] = gelu_f(a);
    }
    __syncthreads();
    float a = eb[t];
    #pragma unroll 8
    for (int j = 0; j < 96; ++j) a += hid[j] * ew[j * C_ + t];
    wse[b * C_ + t] = a;
}

// ---- out = x1 + [cls2*w, y tokens]
__global__ void k_final(const float* __restrict__ x1, const float* __restrict__ y,
    const float* __restrict__ cls2, const float* __restrict__ wse, float* __restrict__ out)
{
    size_t idx = (size_t)blockIdx.x * 256 + threadIdx.x;
    if (idx >= (size_t)B_*N_*C_) return;
    int c = (int)(idx % C_);
    size_t t = idx / C_;
    int n = (int)(t % N_); int b = (int)(t / N_);
    float v = x1[idx];
    if (n == 0) v += cls2[b*C_ + c] * wse[b*C_ + c];
    else        v += y[((size_t)b * P_ + (n - 1)) * C_ + c];
    out[idx] = v;
}

extern "C" void kernel_launch(void* const* d_in, const int* in_sizes, int n_in,
                              void* d_out, int out_size, void* d_ws, size_t ws_size,
                              hipStream_t stream)
{
    const float* x      = (const float*)d_in[0];
    const float* ln1_g  = (const float*)d_in[1];
    const float* ln1_b  = (const float*)d_in[2];
    const float* qkv_w  = (const float*)d_in[3];
    const float* qkv_b  = (const float*)d_in[4];
    const float* proj_w = (const float*)d_in[5];
    const float* proj_b = (const float*)d_in[6];
    const float* ht_w   = (const float*)d_in[7];
    const float* ht_b   = (const float*)d_in[8];
    const float* htn_g  = (const float*)d_in[9];
    const float* htn_b  = (const float*)d_in[10];
    const float* pos    = (const float*)d_in[11];
    const float* ln2_g  = (const float*)d_in[12];
    const float* ln2_b  = (const float*)d_in[13];
    const float* c1_w   = (const float*)d_in[14];
    const float* c1_b   = (const float*)d_in[15];
    const float* bn1_g  = (const float*)d_in[16];
    const float* bn1_b  = (const float*)d_in[17];
    const float* c2_w   = (const float*)d_in[18];
    const float* c2_b   = (const float*)d_in[19];
    const float* bn2_g  = (const float*)d_in[20];
    const float* bn2_b  = (const float*)d_in[21];
    const float* c3_w   = (const float*)d_in[22];
    const float* c3_b   = (const float*)d_in[23];
    const float* bn3_g  = (const float*)d_in[24];
    const float* bn3_b  = (const float*)d_in[25];
    const float* cmp_w  = (const float*)d_in[26];
    const float* cmp_b  = (const float*)d_in[27];
    const float* exc_w  = (const float*)d_in[28];
    const float* exc_b  = (const float*)d_in[29];

    if (ws_size < WS_FLOATS * sizeof(float)) return;
    float* ws  = (float*)d_ws;
    float* XA   = ws + A_OFF;     // (B,M,C)
    float* QKV  = ws + B_OFF;     // (B,M,3C)
    float* AOUT = ws + AOUT_OFF;  // (B,M,C)
    float* PROJ = ws + A_OFF;     // reuse A
    float* X1   = ws + X1_OFF;    // (B,N,C)
    float* XN2  = ws + A_OFF;     // reuse A: (B,196,C)
    float* HBUF = ws + B_OFF;     // reuse B: (B,196,HID)
    float* Y    = ws + A_OFF;     // reuse A: (B,196,C)
    float* CLS2 = ws + CLS2_OFF;
    float* HM   = ws + HM_OFF;
    float* YM   = ws + YM_OFF;
    float* WSE  = ws + WSE_OFF;

    k_ln1<<<(B_*N_ + 3) / 4, 256, 0, stream>>>(x, ln1_g, ln1_b, XA);
    k_head_mean<<<B_, 384, 0, stream>>>(XA, HM);
    k_head_tokens<<<B_, 384, 0, stream>>>(HM, ht_w, ht_b, htn_g, htn_b, pos, XA);

    dim3 gq(TC_/64, (B_*M_)/64);                 // 18 x 406
    k_gemm<0><<<gq, 256, 0, stream>>>(XA, qkv_w, QKV, qkv_b, nullptr, nullptr, C_, TC_);

    k_attn<<<B_*H_, 512, 0, stream>>>(QKV, AOUT);

    dim3 gp(C_/64, (B_*M_)/64);                  // 6 x 406
    k_gemm<0><<<gp, 256, 0, stream>>>(AOUT, proj_w, PROJ, proj_b, nullptr, nullptr, C_, C_);

    k_build_x1<<<(B_*N_*C_ + 255)/256, 256, 0, stream>>>(x, PROJ, X1);
    k_ln2<<<(B_*N_ + 3) / 4, 256, 0, stream>>>(X1, ln2_g, ln2_b, XN2, CLS2);

    dim3 g1(HID_/64, (B_*P_)/64);                // 24 x 392
    k_gemm<1><<<g1, 256, 0, stream>>>(XN2, c1_w, HBUF, c1_b, bn1_g, bn1_b, C_, HID_);

    dim3 gd(B_, HID_/64);                        // 128 x 24
    k_dwconv<<<gd, 256, 0, stream>>>(HBUF, c2_w, c2_b, bn2_g, bn2_b);

    dim3 g3(C_/64, (B_*P_)/64);                  // 6 x 392
    k_gemm<2><<<g3, 256, 0, stream>>>(HBUF, c3_w, Y, c3_b, bn3_g, bn3_b, HID_, C_);

    k_ymean<<<B_, 384, 0, stream>>>(Y, YM);
    k_se<<<B_, 384, 0, stream>>>(YM, cmp_w, cmp_b, exc_w, exc_b, WSE);
    k_final<<<(B_*N_*C_ + 255)/256, 256, 0, stream>>>(X1, Y, CLS2, WSE, (float*)d_out);
}

// Round 3
// 881.747 us; speedup vs baseline: 2.1304x; 2.1304x over previous
//
#include <hip/hip_runtime.h>
#include <math.h>
#include <stdint.h>

// DHVT block. Round 3: bf16-MFMA GEMMs (m97 structure), bf16 activation storage.
// B=128 N=197 C=384 H=6 HD=64 HID=1536 S=14 M=203, Mrows: B*M=25984=128*203, B*P=25088=128*196.
#define B_   128
#define N_   197
#define C_   384
#define H_   6
#define HD_  64
#define HID_ 1536
#define S_   14
#define M_   203
#define P_   196
#define TC_  1152  // 3*C

typedef __bf16 bf16_t;
typedef __bf16 bf16x8 __attribute__((ext_vector_type(8)));
typedef float  f32x4  __attribute__((ext_vector_type(4)));

// ---- workspace layout (bytes). R1: QKV(f32) -> HBUF(bf16). R2: PROJ(f32) -> XN2(bf16) -> Y(f32).
// R3: XA(bf16) -> AOUT(bf16). Total 222.7 MB (prior round proved ws >= 239 MB).
static constexpr size_t R1_OFF   = 0;            // 119,734,272 B
static constexpr size_t R2_OFF   = 119734272;    // 39,911,424 B
static constexpr size_t R3_OFF   = 159645696;    // 19,955,712 B
static constexpr size_t X1_OFF   = 179601408;    // 38,731,776 B (f32)
static constexpr size_t WQ_OFF   = 218333184;    // qkv_wT bf16 [1152][384]
static constexpr size_t WP_OFF   = 219217920;    // proj_wT bf16 [384][384]
static constexpr size_t W1_OFF   = 219512832;    // c1_wT  bf16 [1536][384]
static constexpr size_t W3_OFF   = 220692480;    // c3_wT  bf16 [384][1536]
static constexpr size_t CLS2_OFF = 221872128;    // f32 B*C
static constexpr size_t HM_OFF   = 222068736;    // f32 B*C
static constexpr size_t YM_OFF   = 222265344;    // f32 B*C
static constexpr size_t WSE_OFF  = 222461952;    // f32 B*C
static constexpr size_t WS_BYTES = 222658560;

__device__ __forceinline__ float gelu_f(float x) {
    return 0.5f * x * (1.0f + erff(x * 0.70710678118654752440f));
}
__device__ __forceinline__ float wave_sum(float v) {
    #pragma unroll
    for (int o = 32; o > 0; o >>= 1) v += __shfl_xor(v, o);
    return v;
}
__device__ __forceinline__ float wave_max(float v) {
    #pragma unroll
    for (int o = 32; o > 0; o >>= 1) v = fmaxf(v, __shfl_xor(v, o));
    return v;
}
__device__ __forceinline__ void gl_lds16(const void* g, void* l) {
    __builtin_amdgcn_global_load_lds(
        (const __attribute__((address_space(1))) uint32_t*)g,
        (__attribute__((address_space(3))) uint32_t*)l, 16, 0, 0);
}

// ---- weight transpose + f32->bf16: Wt[n][k] = bf16(W[k][n]). K,N multiples of 32.
__global__ __launch_bounds__(256) void k_wT(const float* __restrict__ W, bf16_t* __restrict__ Wt,
                                            int K, int N)
{
    __shared__ float t[32][33];
    int kb = blockIdx.x * 32, nb = blockIdx.y * 32;
    int tx = threadIdx.x & 31, ty = threadIdx.x >> 5;  // ty 0..7
    #pragma unroll
    for (int i = 0; i < 4; ++i)
        t[ty + i*8][tx] = W[(size_t)(kb + ty + i*8) * N + nb + tx];
    __syncthreads();
    #pragma unroll
    for (int i = 0; i < 4; ++i)
        Wt[(size_t)(nb + ty + i*8) * K + kb + tx] = (bf16_t)t[tx][ty + i*8];
}

// ---- LN over C=384, one wave per row -> bf16 rows [0,197) of xa (B,M,C)
__global__ __launch_bounds__(256) void k_ln1(const float* __restrict__ x,
        const float* __restrict__ g, const float* __restrict__ bt, bf16_t* __restrict__ xa)
{
    int row = blockIdx.x * 4 + (threadIdx.x >> 6);
    if (row >= B_ * N_) return;
    int lane = threadIdx.x & 63;
    int b = row / N_, n = row % N_;
    const float* xr = x + (size_t)row * C_;
    float v[6], s = 0.f, sq = 0.f;
    #pragma unroll
    for (int i = 0; i < 6; ++i) { v[i] = xr[lane + 64*i]; s += v[i]; sq += v[i]*v[i]; }
    s = wave_sum(s); sq = wave_sum(sq);
    float mean = s * (1.0f / C_);
    float var  = sq * (1.0f / C_) - mean * mean;
    float rstd = rsqrtf(var + 1e-5f);
    bf16_t* orow = xa + ((size_t)b * M_ + n) * C_;
    #pragma unroll
    for (int i = 0; i < 6; ++i) {
        int c = lane + 64*i;
        orow[c] = (bf16_t)((v[i] - mean) * rstd * g[c] + bt[c]);
    }
}

// ---- mean over the N=197 normalized tokens -> hm (B,C) f32
__global__ void k_head_mean(const bf16_t* __restrict__ xa, float* __restrict__ hm)
{
    int b = blockIdx.x, c = threadIdx.x;  // 384 threads
    float s = 0.f;
    for (int n = 0; n < N_; ++n) s += (float)xa[((size_t)b * M_ + n) * C_ + c];
    hm[b * C_ + c] = s * (1.0f / N_);
}

// ---- head tokens -> bf16 xa rows [197,203)
__global__ __launch_bounds__(384) void k_head_tokens(const float* __restrict__ hm,
    const float* __restrict__ ht_w, const float* __restrict__ ht_b,
    const float* __restrict__ htn_g, const float* __restrict__ htn_b,
    const float* __restrict__ pos, bf16_t* __restrict__ xa)
{
    __shared__ float hs[C_];
    int b = blockIdx.x, c = threadIdx.x, lane = c & 63;
    hs[c] = hm[b * C_ + c];
    __syncthreads();
    for (int h1 = 0; h1 < H_; ++h1) {
        float acc = ht_b[c];
        #pragma unroll 8
        for (int d = 0; d < HD_; ++d) acc += hs[h1*HD_ + d] * ht_w[d*C_ + c];
        float mean = wave_sum(acc) * (1.0f / HD_);
        float sq   = wave_sum(acc*acc) * (1.0f / HD_);
        float var  = sq - mean*mean;
        float nv = (acc - mean) * rsqrtf(var + 1e-5f) * htn_g[lane] + htn_b[lane];
        xa[((size_t)b*M_ + N_ + h1)*C_ + c] = (bf16_t)(gelu_f(nv) + pos[h1*C_ + c]);
    }
}

// ---- bf16 MFMA GEMM, 128x128 tile, BK=32, 256 threads (4 waves, 2x2), m97 structure.
// A: [Mrows][K] bf16 row-major. Bt: [N][K] bf16 (transposed weight). K,N mult of 128/32; M mult of 128.
// LDS layout [row][slot] with 16B-slot swizzle: content(row,slot) holds global k8 = slot ^ ((row>>1)&3)
// -> both-sides swizzle (G21): pre-swizzled global src + swizzled ds_read = 2-way (free) bank aliasing.
// EPI 0: f32 out = acc+bias ; 1: bf16 out = gelu((acc+bias)*g*R + b) ; 2: f32 out = (acc+bias)*g*R + b
template<int EPI>
__global__ __launch_bounds__(256) void k_mgemm(
    const bf16_t* __restrict__ A, const bf16_t* __restrict__ Bt,
    float* __restrict__ Cf, bf16_t* __restrict__ Cb,
    const float* __restrict__ bias, const float* __restrict__ bng,
    const float* __restrict__ bnb, int K, int Nc)
{
    __shared__ __align__(16) bf16_t As[128*32];
    __shared__ __align__(16) bf16_t Bs[128*32];
    int tid = threadIdx.x;
    int wave = tid >> 6, lane = tid & 63;
    int wm = wave >> 1, wn = wave & 1;
    int m_base = blockIdx.y * 128, n_base = blockIdx.x * 128;

    // staging: thread t -> chunk row sr = t>>2 (0..63), slot ss = t&3; fetch global k8 = ss^((sr>>1)&3)
    int sr = tid >> 2, ss = tid & 3;
    int sk8 = ss ^ ((sr >> 1) & 3);
    const bf16_t* gA = A  + (size_t)(m_base + sr) * K + sk8 * 8;
    const bf16_t* gB = Bt + (size_t)(n_base + sr) * K + sk8 * 8;
    char* AsB = (char*)As; char* BsB = (char*)Bs;

    // per-lane ds_read offsets (swizzle invariant across mf/nf/k-steps)
    int lr = lane & 15, lk = lane >> 4;
    int slot = lk ^ ((lr >> 1) & 3);
    int a_off = wm*4096 + lr*64 + slot*16;
    int b_off = wn*4096 + lr*64 + slot*16;

    f32x4 acc[4][4];
    #pragma unroll
    for (int i = 0; i < 4; ++i)
        #pragma unroll
        for (int j = 0; j < 4; ++j) acc[i][j] = (f32x4){0.f,0.f,0.f,0.f};

    for (int k0 = 0; k0 < K; k0 += 32) {
        gl_lds16(gA + k0,                 AsB + tid*16);
        gl_lds16(gA + k0 + (size_t)64*K,  AsB + 4096 + tid*16);
        gl_lds16(gB + k0,                 BsB + tid*16);
        gl_lds16(gB + k0 + (size_t)64*K,  BsB + 4096 + tid*16);
        __syncthreads();
        bf16x8 af[4], bfr[4];
        #pragma unroll
        for (int i = 0; i < 4; ++i) {
            af[i]  = *(const bf16x8*)(AsB + a_off + i*1024);
            bfr[i] = *(const bf16x8*)(BsB + b_off + i*1024);
        }
        #pragma unroll
        for (int i = 0; i < 4; ++i)
            #pragma unroll
            for (int j = 0; j < 4; ++j)
                acc[i][j] = __builtin_amdgcn_mfma_f32_16x16x32_bf16(af[i], bfr[j], acc[i][j], 0, 0, 0);
        __syncthreads();
    }

    const float R_ = 0.99999500003749969f;  // rsqrt(1+1e-5)
    #pragma unroll
    for (int nf = 0; nf < 4; ++nf) {
        int n = n_base + wn*64 + nf*16 + lr;
        float bia = bias[n];
        float sc = 1.f, sh = 0.f;
        if (EPI >= 1) { sc = bng[n] * R_; sh = bnb[n]; }
        #pragma unroll
        for (int mf = 0; mf < 4; ++mf) {
            size_t mrow = (size_t)m_base + wm*64 + mf*16 + lk*4;
            #pragma unroll
            for (int j = 0; j < 4; ++j) {
                float v = acc[mf][nf][j] + bia;
                if (EPI >= 1) v = v * sc + sh;
                if (EPI == 1) v = gelu_f(v);
                if (EPI == 1) Cb[(mrow + j) * Nc + n] = (bf16_t)v;
                else          Cf[(mrow + j) * Nc + n] = v;
            }
        }
    }
}

// ---- attention: one block per (b,h), 512 threads. QKV f32 in; AOUT bf16 out.
__global__ __launch_bounds__(512) void k_attn(const float* __restrict__ qkv, bf16_t* __restrict__ aout)
{
    __shared__ float Kt[64][204];
    __shared__ float Vs[203][64];
    __shared__ float Pw[8][4][204];
    int b = blockIdx.x / H_, h = blockIdx.x % H_;
    const float* qbase = qkv + (size_t)b * M_ * TC_ + h * HD_;
    for (int idx = threadIdx.x; idx < M_ * 64; idx += 512) {
        int j = idx >> 6, d = idx & 63;
        Kt[d][j] = qbase[(size_t)j * TC_ + 384 + d];
        Vs[j][d] = qbase[(size_t)j * TC_ + 768 + d];
    }
    __syncthreads();
    int wave = threadIdx.x >> 6, lane = threadIdx.x & 63;
    bool lact = (lane < 51);
    for (int mq = wave; mq < 51; mq += 8) {
        int q0 = mq * 4;
        int qidx[4];
        float sc[4][4];
        #pragma unroll
        for (int a = 0; a < 4; ++a) {
            qidx[a] = (q0 + a < M_) ? (q0 + a) : (M_ - 1);
            #pragma unroll
            for (int i = 0; i < 4; ++i) sc[a][i] = 0.f;
        }
        if (lact) {
            #pragma unroll 4
            for (int d = 0; d < 64; d += 4) {
                float4 k0 = *(const float4*)&Kt[d+0][lane*4];
                float4 k1 = *(const float4*)&Kt[d+1][lane*4];
                float4 k2 = *(const float4*)&Kt[d+2][lane*4];
                float4 k3 = *(const float4*)&Kt[d+3][lane*4];
                #pragma unroll
                for (int a = 0; a < 4; ++a) {
                    float4 qv = *(const float4*)(qbase + (size_t)qidx[a] * TC_ + d);
                    sc[a][0] += qv.x*k0.x + qv.y*k1.x + qv.z*k2.x + qv.w*k3.x;
                    sc[a][1] += qv.x*k0.y + qv.y*k1.y + qv.z*k2.y + qv.w*k3.y;
                    sc[a][2] += qv.x*k0.z + qv.y*k1.z + qv.z*k2.z + qv.w*k3.z;
                    sc[a][3] += qv.x*k0.w + qv.y*k1.w + qv.z*k2.w + qv.w*k3.w;
                }
            }
        }
        #pragma unroll
        for (int a = 0; a < 4; ++a) {
            float mx = -1e30f;
            #pragma unroll
            for (int i = 0; i < 4; ++i) {
                int key = lane*4 + i;
                float sv = (lact && key < M_) ? sc[a][i] * 0.125f : -1e30f;
                sc[a][i] = sv;
                mx = fmaxf(mx, sv);
            }
            mx = wave_max(mx);
            float sm = 0.f;
            #pragma unroll
            for (int i = 0; i < 4; ++i) {
                float e = (sc[a][i] > -1e29f) ? __expf(sc[a][i] - mx) : 0.f;
                sc[a][i] = e;
                sm += e;
            }
            sm = wave_sum(sm);
            float inv = 1.0f / sm;
            if (lact) {
                #pragma unroll
                for (int i = 0; i < 4; ++i) Pw[wave][a][lane*4+i] = sc[a][i] * inv;
            }
        }
        asm volatile("s_waitcnt lgkmcnt(0)" ::: "memory");
        float oacc[4] = {0.f, 0.f, 0.f, 0.f};
        for (int j = 0; j < 200; j += 4) {
            float4 p0 = *(const float4*)&Pw[wave][0][j];
            float4 p1 = *(const float4*)&Pw[wave][1][j];
            float4 p2 = *(const float4*)&Pw[wave][2][j];
            float4 p3 = *(const float4*)&Pw[wave][3][j];
            float v0 = Vs[j+0][lane], v1 = Vs[j+1][lane], v2 = Vs[j+2][lane], v3 = Vs[j+3][lane];
            oacc[0] += p0.x*v0 + p0.y*v1 + p0.z*v2 + p0.w*v3;
            oacc[1] += p1.x*v0 + p1.y*v1 + p1.z*v2 + p1.w*v3;
            oacc[2] += p2.x*v0 + p2.y*v1 + p2.z*v2 + p2.w*v3;
            oacc[3] += p3.x*v0 + p3.y*v1 + p3.z*v2 + p3.w*v3;
        }
        #pragma unroll
        for (int j = 200; j < 203; ++j) {
            float v = Vs[j][lane];
            oacc[0] += Pw[wave][0][j] * v;
            oacc[1] += Pw[wave][1][j] * v;
            oacc[2] += Pw[wave][2][j] * v;
            oacc[3] += Pw[wave][3][j] * v;
        }
        #pragma unroll
        for (int a = 0; a < 4; ++a)
            if (q0 + a < M_)
                aout[((size_t)b*M_ + q0 + a)*C_ + h*HD_ + lane] = (bf16_t)oacc[a];
    }
}

// ---- x1 = x + [cls, proj rows 1..196] ; cls = proj[0] + mean(proj rows 197..202)
__global__ void k_build_x1(const float* __restrict__ x, const float* __restrict__ proj,
                           float* __restrict__ x1)
{
    size_t idx = (size_t)blockIdx.x * 256 + threadIdx.x;
    if (idx >= (size_t)B_*N_*C_) return;
    int c = (int)(idx % C_);
    size_t t = idx / C_;
    int n = (int)(t % N_); int b = (int)(t / N_);
    const float* pr = proj + (size_t)b * M_ * C_;
    float v = x[idx];
    if (n == 0) {
        float s = 0.f;
        #pragma unroll
        for (int m = 0; m < H_; ++m) s += pr[(size_t)(N_ + m) * C_ + c];
        v += pr[c] + s * (1.0f / H_);
    } else {
        v += pr[(size_t)n * C_ + c];
    }
    x1[idx] = v;
}

// ---- LN2: row 0 -> cls2 f32 (B,C); rows 1..196 -> xn2 bf16 (B,196,C)
__global__ __launch_bounds__(256) void k_ln2(const float* __restrict__ x1,
    const float* __restrict__ g, const float* __restrict__ bt,
    bf16_t* __restrict__ xn2, float* __restrict__ cls2)
{
    int row = blockIdx.x * 4 + (threadIdx.x >> 6);
    if (row >= B_ * N_) return;
    int lane = threadIdx.x & 63;
    int b = row / N_, n = row % N_;
    const float* xr = x1 + (size_t)row * C_;
    float v[6], s = 0.f, sq = 0.f;
    #pragma unroll
    for (int i = 0; i < 6; ++i) { v[i] = xr[lane + 64*i]; s += v[i]; sq += v[i]*v[i]; }
    s = wave_sum(s); sq = wave_sum(sq);
    float mean = s * (1.0f / C_);
    float var  = sq * (1.0f / C_) - mean * mean;
    float rstd = rsqrtf(var + 1e-5f);
    #pragma unroll
    for (int i = 0; i < 6; ++i) {
        int c = lane + 64*i;
        float ov = (v[i] - mean) * rstd * g[c] + bt[c];
        if (n == 0) cls2[(size_t)b * C_ + c] = ov;
        else        xn2[((size_t)b * P_ + (n - 1)) * C_ + c] = (bf16_t)ov;
    }
}

// ---- depthwise 3x3 SAME + BN + gelu + residual, in place on bf16 h (B,196,HID).
__global__ __launch_bounds__(256) void k_dwconv(bf16_t* __restrict__ h,
    const float* __restrict__ w, const float* __restrict__ c2b,
    const float* __restrict__ g2, const float* __restrict__ b2)
{
    __shared__ float tile[P_][64];
    __shared__ float wl[64][9];
    int b = blockIdx.x, ch0 = blockIdx.y * 64;
    for (int idx = threadIdx.x; idx < P_ * 64; idx += 256) {
        int p = idx >> 6, c = idx & 63;
        tile[p][c] = (float)h[((size_t)b * P_ + p) * HID_ + ch0 + c];
    }
    if (threadIdx.x < 64) {
        int c = threadIdx.x;
        #pragma unroll
        for (int k = 0; k < 9; ++k) wl[c][k] = w[(ch0 + c) * 9 + k];
    }
    __syncthreads();
    const float R_ = 0.99999500003749969f;
    for (int idx = threadIdx.x; idx < P_ * 64; idx += 256) {
        int p = idx >> 6, c = idx & 63;
        int y = p / S_, xq = p % S_;
        float a = 0.f;
        #pragma unroll
        for (int dy = 0; dy < 3; ++dy) {
            int yy = y + dy - 1;
            if (yy < 0 || yy >= S_) continue;
            #pragma unroll
            for (int dx = 0; dx < 3; ++dx) {
                int xx = xq + dx - 1;
                if (xx < 0 || xx >= S_) continue;
                a += wl[c][dy*3+dx] * tile[yy*S_ + xx][c];
            }
        }
        int ch = ch0 + c;
        float val = (a + c2b[ch]) * (g2[ch] * R_) + b2[ch];
        h[((size_t)b * P_ + p) * HID_ + ch] = (bf16_t)(tile[p][c] + gelu_f(val));
    }
}

// ---- spatial mean of y (f32) -> ym (B,C)
__global__ void k_ymean(const float* __restrict__ y, float* __restrict__ ym)
{
    int b = blockIdx.x, c = threadIdx.x;  // 384
    float s = 0.f;
    for (int p = 0; p < P_; ++p) s += y[((size_t)b * P_ + p) * C_ + c];
    ym[b * C_ + c] = s * (1.0f / P_);
}

// ---- SE: w = gelu(ym @ cmp_w + cmp_b) @ exc_w + exc_b
__global__ __launch_bounds__(384) void k_se(const float* __restrict__ ym,
    const float* __restrict__ cw, const float* __restrict__ cb,
    const float* __restrict__ ew, const float* __restrict__ eb, float* __restrict__ wse)
{
    __shared__ float ys[C_];
    __shared__ float hid[96];
    int b = blockIdx.x, t = threadIdx.x;
    ys[t] = ym[b * C_ + t];
    __syncthreads();
    if (t < 96) {
        float a = cb[t];
        for (int c = 0; c < C_; ++c) a += ys[c] * cw[c * 96 + t];
        hid[t] = gelu_f(a);
    }
    __syncthreads();
    float a = eb[t];
    #pragma unroll 8
    for (int j = 0; j < 96; ++j) a += hid[j] * ew[j * C_ + t];
    wse[b * C_ + t] = a;
}

// ---- out = x1 + [cls2*w, y tokens]
__global__ void k_final(const float* __restrict__ x1, const float* __restrict__ y,
    const float* __restrict__ cls2, const float* __restrict__ wse, float* __restrict__ out)
{
    size_t idx = (size_t)blockIdx.x * 256 + threadIdx.x;
    if (idx >= (size_t)B_*N_*C_) return;
    int c = (int)(idx % C_);
    size_t t = idx / C_;
    int n = (int)(t % N_); int b = (int)(t / N_);
    float v = x1[idx];
    if (n == 0) v += cls2[b*C_ + c] * wse[b*C_ + c];
    else        v += y[((size_t)b * P_ + (n - 1)) * C_ + c];
    out[idx] = v;
}

extern "C" void kernel_launch(void* const* d_in, const int* in_sizes, int n_in,
                              void* d_out, int out_size, void* d_ws, size_t ws_size,
                              hipStream_t stream)
{
    const float* x      = (const float*)d_in[0];
    const float* ln1_g  = (const float*)d_in[1];
    const float* ln1_b  = (const float*)d_in[2];
    const float* qkv_w  = (const float*)d_in[3];
    const float* qkv_b  = (const float*)d_in[4];
    const float* proj_w = (const float*)d_in[5];
    const float* proj_b = (const float*)d_in[6];
    const float* ht_w   = (const float*)d_in[7];
    const float* ht_b   = (const float*)d_in[8];
    const float* htn_g  = (const float*)d_in[9];
    const float* htn_b  = (const float*)d_in[10];
    const float* pos    = (const float*)d_in[11];
    const float* ln2_g  = (const float*)d_in[12];
    const float* ln2_b  = (const float*)d_in[13];
    const float* c1_w   = (const float*)d_in[14];
    const float* c1_b   = (const float*)d_in[15];
    const float* bn1_g  = (const float*)d_in[16];
    const float* bn1_b  = (const float*)d_in[17];
    const float* c2_w   = (const float*)d_in[18];
    const float* c2_b   = (const float*)d_in[19];
    const float* bn2_g  = (const float*)d_in[20];
    const float* bn2_b  = (const float*)d_in[21];
    const float* c3_w   = (const float*)d_in[22];
    const float* c3_b   = (const float*)d_in[23];
    const float* bn3_g  = (const float*)d_in[24];
    const float* bn3_b  = (const float*)d_in[25];
    const float* cmp_w  = (const float*)d_in[26];
    const float* cmp_b  = (const float*)d_in[27];
    const float* exc_w  = (const float*)d_in[28];
    const float* exc_b  = (const float*)d_in[29];

    if (ws_size < WS_BYTES) return;  // poisoned output = clear diagnosis
    char* ws = (char*)d_ws;
    float*  QKV  = (float*)(ws + R1_OFF);    // (B,M,3C) f32
    bf16_t* HBUF = (bf16_t*)(ws + R1_OFF);   // (B,196,HID) bf16 (after attn)
    float*  PROJ = (float*)(ws + R2_OFF);    // (B,M,C) f32
    bf16_t* XN2  = (bf16_t*)(ws + R2_OFF);   // (B,196,C) bf16 (after build_x1)
    float*  Y    = (float*)(ws + R2_OFF);    // (B,196,C) f32 (after c1)
    bf16_t* XA   = (bf16_t*)(ws + R3_OFF);   // (B,M,C) bf16
    bf16_t* AOUT = (bf16_t*)(ws + R3_OFF);   // (B,M,C) bf16 (after qkv gemm)
    float*  X1   = (float*)(ws + X1_OFF);
    bf16_t* WQT  = (bf16_t*)(ws + WQ_OFF);
    bf16_t* WPT  = (bf16_t*)(ws + WP_OFF);
    bf16_t* W1T  = (bf16_t*)(ws + W1_OFF);
    bf16_t* W3T  = (bf16_t*)(ws + W3_OFF);
    float*  CLS2 = (float*)(ws + CLS2_OFF);
    float*  HM   = (float*)(ws + HM_OFF);
    float*  YM   = (float*)(ws + YM_OFF);
    float*  WSE  = (float*)(ws + WSE_OFF);

    // weight transposes (independent; cheap)
    k_wT<<<dim3(C_/32,  TC_/32), 256, 0, stream>>>(qkv_w,  WQT, C_,  TC_);
    k_wT<<<dim3(C_/32,  C_/32),  256, 0, stream>>>(proj_w, WPT, C_,  C_);
    k_wT<<<dim3(C_/32,  HID_/32),256, 0, stream>>>(c1_w,   W1T, C_,  HID_);
    k_wT<<<dim3(HID_/32,C_/32),  256, 0, stream>>>(c3_w,   W3T, HID_, C_);

    k_ln1<<<(B_*N_ + 3) / 4, 256, 0, stream>>>(x, ln1_g, ln1_b, XA);
    k_head_mean<<<B_, 384, 0, stream>>>(XA, HM);
    k_head_tokens<<<B_, 384, 0, stream>>>(HM, ht_w, ht_b, htn_g, htn_b, pos, XA);

    k_mgemm<0><<<dim3(TC_/128, (B_*M_)/128), 256, 0, stream>>>(
        XA, WQT, QKV, nullptr, qkv_b, nullptr, nullptr, C_, TC_);

    k_attn<<<B_*H_, 512, 0, stream>>>(QKV, AOUT);

    k_mgemm<0><<<dim3(C_/128, (B_*M_)/128), 256, 0, stream>>>(
        AOUT, WPT, PROJ, nullptr, proj_b, nullptr, nullptr, C_, C_);

    k_build_x1<<<(B_*N_*C_ + 255)/256, 256, 0, stream>>>(x, PROJ, X1);
    k_ln2<<<(B_*N_ + 3) / 4, 256, 0, stream>>>(X1, ln2_g, ln2_b, XN2, CLS2);

    k_mgemm<1><<<dim3(HID_/128, (B_*P_)/128), 256, 0, stream>>>(
        XN2, W1T, nullptr, HBUF, c1_b, bn1_g, bn1_b, C_, HID_);

    k_dwconv<<<dim3(B_, HID_/64), 256, 0, stream>>>(HBUF, c2_w, c2_b, bn2_g, bn2_b);

    k_mgemm<2><<<dim3(C_/128, (B_*P_)/128), 256, 0, stream>>>(
        HBUF, W3T, Y, nullptr, c3_b, bn3_g, bn3_b, HID_, C_);

    k_ymean<<<B_, 384, 0, stream>>>(Y, YM);
    k_se<<<B_, 384, 0, stream>>>(YM, cmp_w, cmp_b, exc_w, exc_b, WSE);
    k_final<<<(B_*N_*C_ + 255)/256, 256, 0, stream>>>(X1, Y, CLS2, WSE, (float*)d_out);
}

// Round 10
// 665.507 us; speedup vs baseline: 2.8226x; 1.3249x over previous
//
#include <hip/hip_runtime.h>
#include <math.h>
#include <stdint.h>

// DHVT block. Round 10: round-4 MFMA-attention kernel + 3 bitwise-neutral
// elementwise fusions (head_mean->head_tokens, ymean->se, build_x1+ln2).
// B=128 N=197 C=384 H=6 HD=64 HID=1536 S=14 M=203. B*M=25984, B*P=25088.
#define B_   128
#define N_   197
#define C_   384
#define H_   6
#define HD_  64
#define HID_ 1536
#define S_   14
#define M_   203
#define P_   196
#define TC_  1152  // 3*C

typedef __bf16 bf16_t;
typedef __bf16 bf16x8 __attribute__((ext_vector_type(8)));
typedef float  f32x4  __attribute__((ext_vector_type(4)));

// ---- workspace layout (bytes). R1: QKV(bf16) -> HBUF(bf16). R2: PROJ(f32) -> XN2(bf16) -> Y(f32).
// R3: XA(bf16) -> AOUT(bf16).
static constexpr size_t R1_OFF   = 0;            // 119,734,272 B
static constexpr size_t R2_OFF   = 119734272;    // 39,911,424 B
static constexpr size_t R3_OFF   = 159645696;    // 19,955,712 B
static constexpr size_t X1_OFF   = 179601408;    // 38,731,776 B (f32)
static constexpr size_t WQ_OFF   = 218333184;    // qkv_wT bf16 [1152][384]
static constexpr size_t WP_OFF   = 219217920;    // proj_wT bf16 [384][384]
static constexpr size_t W1_OFF   = 219512832;    // c1_wT  bf16 [1536][384]
static constexpr size_t W3_OFF   = 220692480;    // c3_wT  bf16 [384][1536]
static constexpr size_t CLS2_OFF = 221872128;    // f32 B*C
static constexpr size_t WSE_OFF  = 222461952;    // f32 B*C
static constexpr size_t WS_BYTES = 222658560;

__device__ __forceinline__ float gelu_f(float x) {
    return 0.5f * x * (1.0f + erff(x * 0.70710678118654752440f));
}
__device__ __forceinline__ float wave_sum(float v) {
    #pragma unroll
    for (int o = 32; o > 0; o >>= 1) v += __shfl_xor(v, o);
    return v;
}
__device__ __forceinline__ void gl_lds16(const void* g, void* l) {
    __builtin_amdgcn_global_load_lds(
        (const __attribute__((address_space(1))) uint32_t*)g,
        (__attribute__((address_space(3))) uint32_t*)l, 16, 0, 0);
}
__device__ __forceinline__ uint32_t pkbf(float a, float b) {
    uint16_t ua = __builtin_bit_cast(uint16_t, (bf16_t)a);
    uint16_t ub = __builtin_bit_cast(uint16_t, (bf16_t)b);
    return (uint32_t)ua | ((uint32_t)ub << 16);
}

// ---- weight transpose + f32->bf16: Wt[n][k] = bf16(W[k][n]). K,N multiples of 32.
__global__ __launch_bounds__(256) void k_wT(const float* __restrict__ W, bf16_t* __restrict__ Wt,
                                            int K, int N)
{
    __shared__ float t[32][33];
    int kb = blockIdx.x * 32, nb = blockIdx.y * 32;
    int tx = threadIdx.x & 31, ty = threadIdx.x >> 5;  // ty 0..7
    #pragma unroll
    for (int i = 0; i < 4; ++i)
        t[ty + i*8][tx] = W[(size_t)(kb + ty + i*8) * N + nb + tx];
    __syncthreads();
    #pragma unroll
    for (int i = 0; i < 4; ++i)
        Wt[(size_t)(nb + ty + i*8) * K + kb + tx] = (bf16_t)t[tx][ty + i*8];
}

// ---- LN over C=384, one wave per row -> bf16 rows [0,197) of xa (B,M,C)
__global__ __launch_bounds__(256) void k_ln1(const float* __restrict__ x,
        const float* __restrict__ g, const float* __restrict__ bt, bf16_t* __restrict__ xa)
{
    int row = blockIdx.x * 4 + (threadIdx.x >> 6);
    if (row >= B_ * N_) return;
    int lane = threadIdx.x & 63;
    int b = row / N_, n = row % N_;
    const float* xr = x + (size_t)row * C_;
    float v[6], s = 0.f, sq = 0.f;
    #pragma unroll
    for (int i = 0; i < 6; ++i) { v[i] = xr[lane + 64*i]; s += v[i]; sq += v[i]*v[i]; }
    s = wave_sum(s); sq = wave_sum(sq);
    float mean = s * (1.0f / C_);
    float var  = sq * (1.0f / C_) - mean * mean;
    float rstd = rsqrtf(var + 1e-5f);
    bf16_t* orow = xa + ((size_t)b * M_ + n) * C_;
    #pragma unroll
    for (int i = 0; i < 6; ++i) {
        int c = lane + 64*i;
        orow[c] = (bf16_t)((v[i] - mean) * rstd * g[c] + bt[c]);
    }
}

// ---- head tokens (FUSED: absorbs head_mean; same summation order -> bitwise-identical hs).
// Reads xa rows [0,197), writes bf16 xa rows [197,203). No read/write overlap.
__global__ __launch_bounds__(384) void k_head_tokens(const bf16_t* __restrict__ xa_in,
    const float* __restrict__ ht_w, const float* __restrict__ ht_b,
    const float* __restrict__ htn_g, const float* __restrict__ htn_b,
    const float* __restrict__ pos, bf16_t* __restrict__ xa)
{
    __shared__ float hs[C_];
    int b = blockIdx.x, c = threadIdx.x, lane = c & 63;
    float s = 0.f;
    for (int n = 0; n < N_; ++n) s += (float)xa_in[((size_t)b * M_ + n) * C_ + c];
    hs[c] = s * (1.0f / N_);
    __syncthreads();
    for (int h1 = 0; h1 < H_; ++h1) {
        float acc = ht_b[c];
        #pragma unroll 8
        for (int d = 0; d < HD_; ++d) acc += hs[h1*HD_ + d] * ht_w[d*C_ + c];
        float mean = wave_sum(acc) * (1.0f / HD_);
        float sq   = wave_sum(acc*acc) * (1.0f / HD_);
        float var  = sq - mean*mean;
        float nv = (acc - mean) * rsqrtf(var + 1e-5f) * htn_g[lane] + htn_b[lane];
        xa[((size_t)b*M_ + N_ + h1)*C_ + c] = (bf16_t)(gelu_f(nv) + pos[h1*C_ + c]);
    }
}

// ---- bf16 MFMA GEMM, 128x128 tile, BK=32, 256 threads (4 waves, 2x2), m97 structure.
// EPI 0: f32 out = acc+bias ; 1: bf16 out = gelu(BN(acc+bias)) ; 2: f32 out = BN(acc+bias) ;
// EPI 3: bf16 out = acc+bias
template<int EPI>
__global__ __launch_bounds__(256) void k_mgemm(
    const bf16_t* __restrict__ A, const bf16_t* __restrict__ Bt,
    float* __restrict__ Cf, bf16_t* __restrict__ Cb,
    const float* __restrict__ bias, const float* __restrict__ bng,
    const float* __restrict__ bnb, int K, int Nc)
{
    __shared__ __align__(16) bf16_t As[128*32];
    __shared__ __align__(16) bf16_t Bs[128*32];
    int tid = threadIdx.x;
    int wave = tid >> 6, lane = tid & 63;
    int wm = wave >> 1, wn = wave & 1;
    int m_base = blockIdx.y * 128, n_base = blockIdx.x * 128;

    int sr = tid >> 2, ss = tid & 3;
    int sk8 = ss ^ ((sr >> 1) & 3);
    const bf16_t* gA = A  + (size_t)(m_base + sr) * K + sk8 * 8;
    const bf16_t* gB = Bt + (size_t)(n_base + sr) * K + sk8 * 8;
    char* AsB = (char*)As; char* BsB = (char*)Bs;

    int lr = lane & 15, lk = lane >> 4;
    int slot = lk ^ ((lr >> 1) & 3);
    int a_off = wm*4096 + lr*64 + slot*16;
    int b_off = wn*4096 + lr*64 + slot*16;

    f32x4 acc[4][4];
    #pragma unroll
    for (int i = 0; i < 4; ++i)
        #pragma unroll
        for (int j = 0; j < 4; ++j) acc[i][j] = (f32x4){0.f,0.f,0.f,0.f};

    for (int k0 = 0; k0 < K; k0 += 32) {
        gl_lds16(gA + k0,                 AsB + tid*16);
        gl_lds16(gA + k0 + (size_t)64*K,  AsB + 4096 + tid*16);
        gl_lds16(gB + k0,                 BsB + tid*16);
        gl_lds16(gB + k0 + (size_t)64*K,  BsB + 4096 + tid*16);
        __syncthreads();
        bf16x8 af[4], bfr[4];
        #pragma unroll
        for (int i = 0; i < 4; ++i) {
            af[i]  = *(const bf16x8*)(AsB + a_off + i*1024);
            bfr[i] = *(const bf16x8*)(BsB + b_off + i*1024);
        }
        #pragma unroll
        for (int i = 0; i < 4; ++i)
            #pragma unroll
            for (int j = 0; j < 4; ++j)
                acc[i][j] = __builtin_amdgcn_mfma_f32_16x16x32_bf16(af[i], bfr[j], acc[i][j], 0, 0, 0);
        __syncthreads();
    }

    const float R_ = 0.99999500003749969f;  // rsqrt(1+1e-5)
    #pragma unroll
    for (int nf = 0; nf < 4; ++nf) {
        int n = n_base + wn*64 + nf*16 + lr;
        float bia = bias[n];
        float sc = 1.f, sh = 0.f;
        if (EPI == 1 || EPI == 2) { sc = bng[n] * R_; sh = bnb[n]; }
        #pragma unroll
        for (int mf = 0; mf < 4; ++mf) {
            size_t mrow = (size_t)m_base + wm*64 + mf*16 + lk*4;
            #pragma unroll
            for (int j = 0; j < 4; ++j) {
                float v = acc[mf][nf][j] + bia;
                if (EPI == 1 || EPI == 2) v = v * sc + sh;
                if (EPI == 1) v = gelu_f(v);
                if (EPI == 1 || EPI == 3) Cb[(mrow + j) * Nc + n] = (bf16_t)v;
                else                      Cf[(mrow + j) * Nc + n] = v;
            }
        }
    }
}

// ---- MFMA attention: one block per (b,h), 512 threads (8 waves).
// QKV bf16 in (B,M,3C); AOUT bf16 out (B,M,C).
// S^T = mfma(K,Q): C/D col=q(lane&15), row=key((lane>>4)*4+j). Keys padded to 224, masked >=203.
// P rearranged C/D->A-frag in-register via 8 shfl + 4 sel per 32-key chunk; O = mfma(P, Vt).
__global__ __launch_bounds__(512) void k_attn_mfma(const bf16_t* __restrict__ qkv,
                                                   bf16_t* __restrict__ aout)
{
    __shared__ __align__(16) bf16_t Ks[224*64];   // content(r,s) = K[r][8*(s^(r&7)) ..+7]
    __shared__ __align__(16) bf16_t Vt[64][232];  // Vt[d][k] = V[k][d]; k>=203 zeroed
    int b = blockIdx.x / H_, h = blockIdx.x % H_;
    const bf16_t* qb = qkv + (size_t)b * M_ * TC_ + h * HD_;
    const bf16_t* kb = qb + C_;
    const bf16_t* vb = qb + 2 * C_;
    int tid = threadIdx.x;

    // stage K: 224 rows x 8 slots of 16B; linear LDS dest, swizzled global src (G21)
    #pragma unroll
    for (int it = 0; it < 4; ++it) {
        int idx = tid + it * 512;
        if (idx < 1792) {
            int r = idx >> 3, s = idx & 7;
            int sg = s ^ (r & 7);
            gl_lds16(kb + (size_t)r * TC_ + sg * 8, ((char*)Ks) + idx * 16);
        }
    }
    // stage Vt (transpose, zero-pad)
    {
        int d0 = (tid & 31) * 2;
        uint16_t* vt0 = (uint16_t*)&Vt[d0][0];
        uint16_t* vt1 = (uint16_t*)&Vt[d0 + 1][0];
        for (int k = tid >> 5; k < 224; k += 16) {
            uint32_t u = 0;
            if (k < M_) u = *(const uint32_t*)(vb + (size_t)k * TC_ + d0);
            vt0[k] = (uint16_t)(u & 0xffff);
            vt1[k] = (uint16_t)(u >> 16);
        }
    }
    __syncthreads();

    int lane = tid & 63, wave = tid >> 6;
    int q16 = lane & 15, g = lane >> 4;
    int base4g = g * 4;
    int s0 = q16 + (g & 1) * 32, s1 = s0 + 16;
    bool sel = (lane >= 32);

    for (int qt = wave; qt < 13; qt += 8) {
        // Q b-frags from global (L2-resident)
        int qrow = qt * 16 + q16;
        bf16x8 qf0 = *(const bf16x8*)(qb + (size_t)qrow * TC_ + g * 8);
        bf16x8 qf1 = *(const bf16x8*)(qb + (size_t)qrow * TC_ + 32 + g * 8);

        f32x4 sacc[14];
        #pragma unroll
        for (int t = 0; t < 14; ++t) sacc[t] = (f32x4){0.f, 0.f, 0.f, 0.f};
        #pragma unroll
        for (int kt = 0; kt < 14; ++kt) {
            int r = kt * 16 + q16;
            const char* rowp = (const char*)Ks + r * 128;
            bf16x8 kf0 = *(const bf16x8*)(rowp + ((g ^ (r & 7)) * 16));
            bf16x8 kf1 = *(const bf16x8*)(rowp + (((4 + g) ^ (r & 7)) * 16));
            sacc[kt] = __builtin_amdgcn_mfma_f32_16x16x32_bf16(kf0, qf0, sacc[kt], 0, 0, 0);
            sacc[kt] = __builtin_amdgcn_mfma_f32_16x16x32_bf16(kf1, qf1, sacc[kt], 0, 0, 0);
        }

        // softmax over keys (values for query q live in lanes q, q+16, q+32, q+48)
        float mx = -1e30f;
        #pragma unroll
        for (int t = 0; t < 14; ++t)
            #pragma unroll
            for (int j = 0; j < 4; ++j) {
                int key = 16 * t + base4g + j;
                float v = (key < M_) ? sacc[t][j] * 0.125f : -1e30f;
                sacc[t][j] = v;
                mx = fmaxf(mx, v);
            }
        mx = fmaxf(mx, __shfl_xor(mx, 16));
        mx = fmaxf(mx, __shfl_xor(mx, 32));
        float sm = 0.f;
        #pragma unroll
        for (int t = 0; t < 14; ++t)
            #pragma unroll
            for (int j = 0; j < 4; ++j) {
                float e = __expf(sacc[t][j] - mx);
                sacc[t][j] = e;
                sm += e;
            }
        sm += __shfl_xor(sm, 16);
        sm += __shfl_xor(sm, 32);
        float inv = 1.0f / sm;

        uint32_t plo[14], phi[14];
        #pragma unroll
        for (int t = 0; t < 14; ++t) {
            plo[t] = pkbf(sacc[t][0] * inv, sacc[t][1] * inv);
            phi[t] = pkbf(sacc[t][2] * inv, sacc[t][3] * inv);
        }

        // PV: O[q][d], 7 key-chunks of 32
        f32x4 oacc[4];
        #pragma unroll
        for (int dt = 0; dt < 4; ++dt) oacc[dt] = (f32x4){0.f, 0.f, 0.f, 0.f};
        #pragma unroll
        for (int c = 0; c < 7; ++c) {
            uint32_t l0a = (uint32_t)__shfl((int)plo[2*c],     s0);
            uint32_t l1a = (uint32_t)__shfl((int)plo[2*c + 1], s0);
            uint32_t h0a = (uint32_t)__shfl((int)phi[2*c],     s0);
            uint32_t h1a = (uint32_t)__shfl((int)phi[2*c + 1], s0);
            uint32_t l0b = (uint32_t)__shfl((int)plo[2*c],     s1);
            uint32_t l1b = (uint32_t)__shfl((int)plo[2*c + 1], s1);
            uint32_t h0b = (uint32_t)__shfl((int)phi[2*c],     s1);
            uint32_t h1b = (uint32_t)__shfl((int)phi[2*c + 1], s1);
            union { uint32_t u[4]; bf16x8 v; } pf;
            pf.u[0] = sel ? l1a : l0a;
            pf.u[1] = sel ? h1a : h0a;
            pf.u[2] = sel ? l1b : l0b;
            pf.u[3] = sel ? h1b : h0b;
            #pragma unroll
            for (int dt = 0; dt < 4; ++dt) {
                bf16x8 vf = *(const bf16x8*)(&Vt[dt*16 + q16][c*32 + g*8]);
                oacc[dt] = __builtin_amdgcn_mfma_f32_16x16x32_bf16(pf.v, vf, oacc[dt], 0, 0, 0);
            }
        }

        // store: row q = qt*16 + g*4 + j, col d = dt*16 + q16
        #pragma unroll
        for (int dt = 0; dt < 4; ++dt)
            #pragma unroll
            for (int j = 0; j < 4; ++j) {
                int q = qt * 16 + base4g + j;
                if (q < M_)
                    aout[((size_t)b * M_ + q) * C_ + h * HD_ + dt * 16 + q16] = (bf16_t)oacc[dt][j];
            }
    }
}

// ---- FUSED build_x1 + LN2. One wave per row. Computes x1 row once in registers
// (identical expression to the old k_build_x1, wave-uniform n==0 branch), writes x1,
// then LN with the same per-lane accumulation order as the old k_ln2 -> bitwise-identical.
__global__ __launch_bounds__(256) void k_x1ln2(const float* __restrict__ x,
    const float* __restrict__ proj, const float* __restrict__ g, const float* __restrict__ bt,
    float* __restrict__ x1, bf16_t* __restrict__ xn2, float* __restrict__ cls2)
{
    int row = blockIdx.x * 4 + (threadIdx.x >> 6);
    if (row >= B_ * N_) return;
    int lane = threadIdx.x & 63;
    int b = row / N_, n = row % N_;
    const float* xr = x + (size_t)row * C_;
    const float* pr = proj + (size_t)b * M_ * C_;
    float v[6], s = 0.f, sq = 0.f;
    #pragma unroll
    for (int i = 0; i < 6; ++i) {
        int c = lane + 64*i;
        float t;
        if (n == 0) {
            float m = 0.f;
            #pragma unroll
            for (int mm = 0; mm < H_; ++mm) m += pr[(size_t)(N_ + mm) * C_ + c];
            t = xr[c] + pr[c] + m * (1.0f / H_);
        } else {
            t = xr[c] + pr[(size_t)n * C_ + c];
        }
        v[i] = t; s += t; sq += t*t;
    }
    float* x1r = x1 + (size_t)row * C_;
    #pragma unroll
    for (int i = 0; i < 6; ++i) x1r[lane + 64*i] = v[i];
    s = wave_sum(s); sq = wave_sum(sq);
    float mean = s * (1.0f / C_);
    float var  = sq * (1.0f / C_) - mean * mean;
    float rstd = rsqrtf(var + 1e-5f);
    #pragma unroll
    for (int i = 0; i < 6; ++i) {
        int c = lane + 64*i;
        float ov = (v[i] - mean) * rstd * g[c] + bt[c];
        if (n == 0) cls2[(size_t)b * C_ + c] = ov;
        else        xn2[((size_t)b * P_ + (n - 1)) * C_ + c] = (bf16_t)ov;
    }
}

// ---- depthwise 3x3 SAME + BN + gelu + residual, in place on bf16 h (B,196,HID).
__global__ __launch_bounds__(256) void k_dwconv(bf16_t* __restrict__ h,
    const float* __restrict__ w, const float* __restrict__ c2b,
    const float* __restrict__ g2, const float* __restrict__ b2)
{
    __shared__ float tile[P_][64];
    __shared__ float wl[64][9];
    int b = blockIdx.x, ch0 = blockIdx.y * 64;
    for (int idx = threadIdx.x; idx < P_ * 64; idx += 256) {
        int p = idx >> 6, c = idx & 63;
        tile[p][c] = (float)h[((size_t)b * P_ + p) * HID_ + ch0 + c];
    }
    if (threadIdx.x < 64) {
        int c = threadIdx.x;
        #pragma unroll
        for (int k = 0; k < 9; ++k) wl[c][k] = w[(ch0 + c) * 9 + k];
    }
    __syncthreads();
    const float R_ = 0.99999500003749969f;
    for (int idx = threadIdx.x; idx < P_ * 64; idx += 256) {
        int p = idx >> 6, c = idx & 63;
        int y = p / S_, xq = p % S_;
        float a = 0.f;
        #pragma unroll
        for (int dy = 0; dy < 3; ++dy) {
            int yy = y + dy - 1;
            if (yy < 0 || yy >= S_) continue;
            #pragma unroll
            for (int dx = 0; dx < 3; ++dx) {
                int xx = xq + dx - 1;
                if (xx < 0 || xx >= S_) continue;
                a += wl[c][dy*3+dx] * tile[yy*S_ + xx][c];
            }
        }
        int ch = ch0 + c;
        float val = (a + c2b[ch]) * (g2[ch] * R_) + b2[ch];
        h[((size_t)b * P_ + p) * HID_ + ch] = (bf16_t)(tile[p][c] + gelu_f(val));
    }
}

// ---- SE (FUSED: absorbs ymean; same summation order -> bitwise-identical ys).
__global__ __launch_bounds__(384) void k_se(const float* __restrict__ y,
    const float* __restrict__ cw, const float* __restrict__ cb,
    const float* __restrict__ ew, const float* __restrict__ eb, float* __restrict__ wse)
{
    __shared__ float ys[C_];
    __shared__ float hid[96];
    int b = blockIdx.x, t = threadIdx.x;
    float s = 0.f;
    for (int p = 0; p < P_; ++p) s += y[((size_t)b * P_ + p) * C_ + t];
    ys[t] = s * (1.0f / P_);
    __syncthreads();
    if (t < 96) {
        float a = cb[t];
        for (int c = 0; c < C_; ++c) a += ys[c] * cw[c * 96 + t];
        hid[t] = gelu_f(a);
    }
    __syncthreads();
    float a = eb[t];
    #pragma unroll 8
    for (int j = 0; j < 96; ++j) a += hid[j] * ew[j * C_ + t];
    wse[b * C_ + t] = a;
}

// ---- out = x1 + [cls2*w, y tokens]
__global__ void k_final(const float* __restrict__ x1, const float* __restrict__ y,
    const float* __restrict__ cls2, const float* __restrict__ wse, float* __restrict__ out)
{
    size_t idx = (size_t)blockIdx.x * 256 + threadIdx.x;
    if (idx >= (size_t)B_*N_*C_) return;
    int c = (int)(idx % C_);
    size_t t = idx / C_;
    int n = (int)(t % N_); int b = (int)(t / N_);
    float v = x1[idx];
    if (n == 0) v += cls2[b*C_ + c] * wse[b*C_ + c];
    else        v += y[((size_t)b * P_ + (n - 1)) * C_ + c];
    out[idx] = v;
}

extern "C" void kernel_launch(void* const* d_in, const int* in_sizes, int n_in,
                              void* d_out, int out_size, void* d_ws, size_t ws_size,
                              hipStream_t stream)
{
    const float* x      = (const float*)d_in[0];
    const float* ln1_g  = (const float*)d_in[1];
    const float* ln1_b  = (const float*)d_in[2];
    const float* qkv_w  = (const float*)d_in[3];
    const float* qkv_b  = (const float*)d_in[4];
    const float* proj_w = (const float*)d_in[5];
    const float* proj_b = (const float*)d_in[6];
    const float* ht_w   = (const float*)d_in[7];
    const float* ht_b   = (const float*)d_in[8];
    const float* htn_g  = (const float*)d_in[9];
    const float* htn_b  = (const float*)d_in[10];
    const float* pos    = (const float*)d_in[11];
    const float* ln2_g  = (const float*)d_in[12];
    const float* ln2_b  = (const float*)d_in[13];
    const float* c1_w   = (const float*)d_in[14];
    const float* c1_b   = (const float*)d_in[15];
    const float* bn1_g  = (const float*)d_in[16];
    const float* bn1_b  = (const float*)d_in[17];
    const float* c2_w   = (const float*)d_in[18];
    const float* c2_b   = (const float*)d_in[19];
    const float* bn2_g  = (const float*)d_in[20];
    const float* bn2_b  = (const float*)d_in[21];
    const float* c3_w   = (const float*)d_in[22];
    const float* c3_b   = (const float*)d_in[23];
    const float* bn3_g  = (const float*)d_in[24];
    const float* bn3_b  = (const float*)d_in[25];
    const float* cmp_w  = (const float*)d_in[26];
    const float* cmp_b  = (const float*)d_in[27];
    const float* exc_w  = (const float*)d_in[28];
    const float* exc_b  = (const float*)d_in[29];

    if (ws_size < WS_BYTES) return;
    char* ws = (char*)d_ws;
    bf16_t* QKVb = (bf16_t*)(ws + R1_OFF);   // (B,M,3C) bf16
    bf16_t* HBUF = (bf16_t*)(ws + R1_OFF);   // (B,196,HID) bf16 (after attn)
    float*  PROJ = (float*)(ws + R2_OFF);    // (B,M,C) f32
    bf16_t* XN2  = (bf16_t*)(ws + R2_OFF);   // (B,196,C) bf16 (after x1ln2)
    float*  Y    = (float*)(ws + R2_OFF);    // (B,196,C) f32 (after c1 consumed XN2... Y written by c3)
    bf16_t* XA   = (bf16_t*)(ws + R3_OFF);   // (B,M,C) bf16
    bf16_t* AOUT = (bf16_t*)(ws + R3_OFF);   // (B,M,C) bf16 (after qkv gemm)
    float*  X1   = (float*)(ws + X1_OFF);
    bf16_t* WQT  = (bf16_t*)(ws + WQ_OFF);
    bf16_t* WPT  = (bf16_t*)(ws + WP_OFF);
    bf16_t* W1T  = (bf16_t*)(ws + W1_OFF);
    bf16_t* W3T  = (bf16_t*)(ws + W3_OFF);
    float*  CLS2 = (float*)(ws + CLS2_OFF);
    float*  WSE  = (float*)(ws + WSE_OFF);

    k_wT<<<dim3(C_/32,  TC_/32), 256, 0, stream>>>(qkv_w,  WQT, C_,  TC_);
    k_wT<<<dim3(C_/32,  C_/32),  256, 0, stream>>>(proj_w, WPT, C_,  C_);
    k_wT<<<dim3(C_/32,  HID_/32),256, 0, stream>>>(c1_w,   W1T, C_,  HID_);
    k_wT<<<dim3(HID_/32,C_/32),  256, 0, stream>>>(c3_w,   W3T, HID_, C_);

    k_ln1<<<(B_*N_ + 3) / 4, 256, 0, stream>>>(x, ln1_g, ln1_b, XA);
    k_head_tokens<<<B_, 384, 0, stream>>>(XA, ht_w, ht_b, htn_g, htn_b, pos, XA);

    k_mgemm<3><<<dim3(TC_/128, (B_*M_)/128), 256, 0, stream>>>(
        XA, WQT, nullptr, QKVb, qkv_b, nullptr, nullptr, C_, TC_);

    k_attn_mfma<<<B_*H_, 512, 0, stream>>>(QKVb, AOUT);

    k_mgemm<0><<<dim3(C_/128, (B_*M_)/128), 256, 0, stream>>>(
        AOUT, WPT, PROJ, nullptr, proj_b, nullptr, nullptr, C_, C_);

    k_x1ln2<<<(B_*N_ + 3) / 4, 256, 0, stream>>>(x, PROJ, ln2_g, ln2_b, X1, XN2, CLS2);

    k_mgemm<1><<<dim3(HID_/128, (B_*P_)/128), 256, 0, stream>>>(
        XN2, W1T, nullptr, HBUF, c1_b, bn1_g, bn1_b, C_, HID_);

    k_dwconv<<<dim3(B_, HID_/64), 256, 0, stream>>>(HBUF, c2_w, c2_b, bn2_g, bn2_b);

    k_mgemm<2><<<dim3(C_/128, (B_*P_)/128), 256, 0, stream>>>(
        HBUF, W3T, Y, nullptr, c3_b, bn3_g, bn3_b, HID_, C_);

    k_se<<<B_, 384, 0, stream>>>(Y, cmp_w, cmp_b, exc_w, exc_b, WSE);
    k_final<<<(B_*N_*C_ + 255)/256, 256, 0, stream>>>(X1, Y, CLS2, WSE, (float*)d_out);
}